// Round 1
// baseline (883.403 us; speedup 1.0000x reference)
//
#include <hip/hip_runtime.h>

// Problem constants
#define B_SZ   32
#define C_SZ   256          // == D
#define HW_SZ  1024         // H*W = 32*32
#define N_PTS  32768        // B*H*W
#define KCODES 1024
#define DDIM   256

#define OUT_ELEMS 8388608   // B*C*H*W
#define LOSS_OFF  8388608
#define ENT_OFF   8388609
#define ENC_OFF   8388610   // encodings [N, K] start

// ---------------------------------------------------------------------------
// prep: wnorm[k] = ||w_k||^2 ; zero counts ; zero loss/entropy slots
// ---------------------------------------------------------------------------
__global__ void prep_kernel(const float* __restrict__ w, float* __restrict__ wnorm,
                            int* __restrict__ counts, float* __restrict__ out) {
    int k = blockIdx.x * 256 + threadIdx.x;
    if (k < KCODES) {
        const float4* wr = (const float4*)(w + (long)k * DDIM);
        float s = 0.f;
#pragma unroll 8
        for (int i = 0; i < DDIM / 4; ++i) {
            float4 v = wr[i];
            s += v.x * v.x + v.y * v.y + v.z * v.z + v.w * v.w;
        }
        wnorm[k]  = s;
        counts[k] = 0;
    }
    if (blockIdx.x == 0 && threadIdx.x == 0) {
        out[LOSS_OFF] = 0.f;
        out[ENT_OFF]  = 0.f;
    }
}

// ---------------------------------------------------------------------------
// argmin kernel: per block 128 points x all 1024 codes.
// SGEMM-style: 256 threads, 8x8 register tile each, D staged in 16-chunks.
// dist_k (shifted) = wnorm[k] - 2 * dot(x_n, w_k); keep running (best, idx).
// ---------------------------------------------------------------------------
#define NT 128
#define KT 128
#define DK 16

__global__ __launch_bounds__(256)
void argmin_kernel(const float* __restrict__ x, const float* __restrict__ w,
                   const float* __restrict__ wnorm,
                   int* __restrict__ idx_out, int* __restrict__ counts) {
    __shared__ float As[DK][NT];   // 8 KB
    __shared__ float Bs[DK][KT];   // 8 KB
    __shared__ float rv[NT][16];   // 8 KB
    __shared__ int   ri[NT][16];   // 8 KB

    const int tid = threadIdx.x;       // 0..255
    const int tx  = tid & 15;          // code group
    const int ty  = tid >> 4;          // point group
    const int n0  = blockIdx.x * NT;   // first point of this block
    const int b   = n0 >> 10;          // 1024 points per batch image
    const int hw0 = n0 & 1023;
    // x is BCHW: x[b][d][hw] -> point n=b*1024+hw has feature d at stride HW
    const float* xbase = x + (long)b * (C_SZ * HW_SZ) + hw0;

    float best[8];
    int   bidx[8];
#pragma unroll
    for (int i = 0; i < 8; ++i) { best[i] = 3.402823466e38f; bidx[i] = 0; }

    for (int kc = 0; kc < KCODES; kc += KT) {
        float acc[8][8];
#pragma unroll
        for (int i = 0; i < 8; ++i)
#pragma unroll
            for (int j = 0; j < 8; ++j) acc[i][j] = 0.f;

        for (int dc = 0; dc < DDIM; dc += DK) {
            // Stage A: 16 dims x 128 points (coalesced: points contiguous)
#pragma unroll
            for (int l = 0; l < 2; ++l) {
                int t  = tid + l * 256;        // 0..511
                int d  = t >> 5;               // 0..15
                int i4 = (t & 31) * 4;         // 0..124
                float4 v = *(const float4*)(xbase + (long)(dc + d) * HW_SZ + i4);
                *(float4*)&As[d][i4] = v;
            }
            // Stage B: 128 codes x 16 dims, transposed into [d][k]
#pragma unroll
            for (int l = 0; l < 2; ++l) {
                int t  = tid + l * 256;        // 0..511
                int k  = t >> 2;               // 0..127
                int dq = (t & 3) * 4;          // 0,4,8,12
                float4 v = *(const float4*)(w + (long)(kc + k) * DDIM + dc + dq);
                Bs[dq + 0][k] = v.x;
                Bs[dq + 1][k] = v.y;
                Bs[dq + 2][k] = v.z;
                Bs[dq + 3][k] = v.w;
            }
            __syncthreads();
#pragma unroll
            for (int d = 0; d < DK; ++d) {
                float a[8], bb[8];
                *(float4*)&a[0]  = *(const float4*)&As[d][ty * 8];
                *(float4*)&a[4]  = *(const float4*)&As[d][ty * 8 + 4];
                *(float4*)&bb[0] = *(const float4*)&Bs[d][tx * 8];
                *(float4*)&bb[4] = *(const float4*)&Bs[d][tx * 8 + 4];
#pragma unroll
                for (int i = 0; i < 8; ++i)
#pragma unroll
                    for (int j = 0; j < 8; ++j) acc[i][j] += a[i] * bb[j];
            }
            __syncthreads();
        }

        // fold this K-chunk into running best (ascending k order => first-min tie-break)
#pragma unroll
        for (int j = 0; j < 8; ++j) {
            int   k  = kc + tx * 8 + j;
            float wn = wnorm[k];
#pragma unroll
            for (int i = 0; i < 8; ++i) {
                float dist = wn - 2.0f * acc[i][j];
                if (dist < best[i]) { best[i] = dist; bidx[i] = k; }
            }
        }
    }

    // cross-tx argmin reduction via LDS
#pragma unroll
    for (int i = 0; i < 8; ++i) {
        rv[ty * 8 + i][tx] = best[i];
        ri[ty * 8 + i][tx] = bidx[i];
    }
    __syncthreads();
    if (tid < NT) {
        float bv = rv[tid][0];
        int   bi = ri[tid][0];
#pragma unroll
        for (int t = 1; t < 16; ++t) {
            float v  = rv[tid][t];
            int   ii = ri[tid][t];
            if (v < bv || (v == bv && ii < bi)) { bv = v; bi = ii; }
        }
        idx_out[n0 + tid] = bi;
        atomicAdd(&counts[bi], 1);
    }
}

// ---------------------------------------------------------------------------
// gather: out[b][c][hw] = w[idx[n]][c] ; fused commitment-loss reduction
// ---------------------------------------------------------------------------
__global__ __launch_bounds__(256)
void gather_kernel(const float* __restrict__ x, const float* __restrict__ w,
                   const int* __restrict__ idx, float* __restrict__ out,
                   float* __restrict__ loss) {
    const int i  = blockIdx.x * 256 + threadIdx.x;   // < 8388608
    const int hw = i & 1023;
    const int c  = (i >> 10) & 255;
    const int b  = i >> 18;
    const int n  = (b << 10) + hw;

    float q  = w[(long)idx[n] * DDIM + c];
    float xv = x[i];
    out[i] = q;
    float d = q - xv;
    float e = d * d;

    // wave64 reduce
#pragma unroll
    for (int off = 32; off > 0; off >>= 1) e += __shfl_down(e, off, 64);
    __shared__ float wsum[4];
    int lane = threadIdx.x & 63, wid = threadIdx.x >> 6;
    if (lane == 0) wsum[wid] = e;
    __syncthreads();
    if (threadIdx.x == 0) {
        float s = wsum[0] + wsum[1] + wsum[2] + wsum[3];
        atomicAdd(loss, s * (0.25f / (float)OUT_ELEMS));
    }
}

// ---------------------------------------------------------------------------
// encodings: one-hot [N, K] float32 — 4 floats per thread, float2 stores
// (enc base is only 8-byte aligned: ENC_OFF % 4 == 2)
// ---------------------------------------------------------------------------
__global__ __launch_bounds__(256)
void enc_kernel(const int* __restrict__ idx, float* __restrict__ enc) {
    const int t = blockIdx.x * 256 + threadIdx.x;    // < 8388608
    const int j = t * 4;
    const int n = j >> 10;
    const int k = j & 1023;
    const int id = idx[n];
    float2 v0, v1;
    v0.x = (k == id)     ? 1.f : 0.f;
    v0.y = (k + 1 == id) ? 1.f : 0.f;
    v1.x = (k + 2 == id) ? 1.f : 0.f;
    v1.y = (k + 3 == id) ? 1.f : 0.f;
    float2* p = (float2*)(enc + j);
    p[0] = v0;
    p[1] = v1;
}

// ---------------------------------------------------------------------------
// entropy: -sum p*log(p+1e-10), p = counts/N
// ---------------------------------------------------------------------------
__global__ void entropy_kernel(const int* __restrict__ counts, float* __restrict__ out) {
    __shared__ float red[256];
    float s = 0.f;
#pragma unroll
    for (int l = 0; l < 4; ++l) {
        int k = threadIdx.x + l * 256;
        float p = (float)counts[k] * (1.0f / (float)N_PTS);
        s += p * logf(p + 1e-10f);
    }
    red[threadIdx.x] = s;
    __syncthreads();
    for (int off = 128; off > 0; off >>= 1) {
        if (threadIdx.x < off) red[threadIdx.x] += red[threadIdx.x + off];
        __syncthreads();
    }
    if (threadIdx.x == 0) out[ENT_OFF] = -red[0];
}

// ---------------------------------------------------------------------------
extern "C" void kernel_launch(void* const* d_in, const int* in_sizes, int n_in,
                              void* d_out, int out_size, void* d_ws, size_t ws_size,
                              hipStream_t stream) {
    const float* x = (const float*)d_in[0];   // [32,256,32,32] BCHW
    const float* w = (const float*)d_in[1];   // [1024,256]
    float* out = (float*)d_out;

    int*   idx    = (int*)d_ws;               // [32768]
    int*   counts = idx + N_PTS;              // [1024]
    float* wnorm  = (float*)(counts + KCODES);// [1024]

    prep_kernel<<<4, 256, 0, stream>>>(w, wnorm, counts, out);
    argmin_kernel<<<N_PTS / NT, 256, 0, stream>>>(x, w, wnorm, idx, counts);
    gather_kernel<<<OUT_ELEMS / 256, 256, 0, stream>>>(x, w, idx, out, out + LOSS_OFF);
    enc_kernel<<<OUT_ELEMS / 256, 256, 0, stream>>>(idx, out + ENC_OFF);
    entropy_kernel<<<1, 256, 0, stream>>>(counts, out);
}

// Round 2
// 452.196 us; speedup vs baseline: 1.9536x; 1.9536x over previous
//
#include <hip/hip_runtime.h>

// Problem constants
#define B_SZ   32
#define C_SZ   256          // == D
#define HW_SZ  1024         // H*W
#define N_PTS  32768        // B*H*W
#define KCODES 1024
#define DDIM   256

#define OUT_ELEMS 8388608   // B*C*H*W
#define LOSS_OFF  8388608
#define ENT_OFF   8388609
#define ENC_OFF   8388610   // encodings [N, K] start

#define NT 128              // points per block
#define KT 128              // codes per LDS chunk
#define DK 16               // dims per LDS chunk
#define KSPLIT 4            // K-dimension block split (occupancy)
#define KSPAN  256          // codes per block = KCODES/KSPLIT

#define GATHER_BLOCKS 1024
#define GATHER_THREADS_TOT (GATHER_BLOCKS * 256)   // 262144

// ---------------------------------------------------------------------------
// prep: wnorm[k] = ||w_k||^2 ; zero counts
// ---------------------------------------------------------------------------
__global__ void prep_kernel(const float* __restrict__ w, float* __restrict__ wnorm,
                            int* __restrict__ counts) {
    int k = blockIdx.x * 256 + threadIdx.x;
    if (k < KCODES) {
        const float4* wr = (const float4*)(w + (long)k * DDIM);
        float s = 0.f;
#pragma unroll 8
        for (int i = 0; i < DDIM / 4; ++i) {
            float4 v = wr[i];
            s += v.x * v.x + v.y * v.y + v.z * v.z + v.w * v.w;
        }
        wnorm[k]  = s;
        counts[k] = 0;
    }
}

// ---------------------------------------------------------------------------
// argmin kernel: block = 128 points x 256 codes (K-split by blockIdx.y).
// SGEMM-style 8x8 register tiles; candidates written per split, merged later.
// LDS: As|Bs (16 KB) overlaid by the reduction arrays after compute.
// ---------------------------------------------------------------------------
__global__ __launch_bounds__(256)
void argmin_kernel(const float* __restrict__ x, const float* __restrict__ w,
                   const float* __restrict__ wnorm,
                   float* __restrict__ candv, int* __restrict__ candi) {
    __shared__ float smem[4160];           // max(As+Bs = 4096, rv+ri = 4128)
    float* As = smem;                      // [DK][NT]
    float* Bs = smem + DK * NT;            // [DK][KT]

    const int tid = threadIdx.x;           // 0..255
    const int tx  = tid & 15;              // code group
    const int ty  = tid >> 4;              // point group
    const int n0  = blockIdx.x * NT;
    const int ks  = blockIdx.y;            // 0..3 (K split)
    const int b   = n0 >> 10;
    const int hw0 = n0 & 1023;
    const float* xbase = x + (long)b * (C_SZ * HW_SZ) + hw0;

    float best[8];
    int   bidx[8];
#pragma unroll
    for (int i = 0; i < 8; ++i) { best[i] = 3.402823466e38f; bidx[i] = 0; }

    for (int kc = ks * KSPAN; kc < ks * KSPAN + KSPAN; kc += KT) {
        float acc[8][8];
#pragma unroll
        for (int i = 0; i < 8; ++i)
#pragma unroll
            for (int j = 0; j < 8; ++j) acc[i][j] = 0.f;

        for (int dc = 0; dc < DDIM; dc += DK) {
            // Stage A: 16 dims x 128 points (points contiguous in x => coalesced)
#pragma unroll
            for (int l = 0; l < 2; ++l) {
                int t  = tid + l * 256;          // 0..511
                int d  = t >> 5;                 // 0..15
                int i4 = (t & 31) * 4;           // 0..124
                float4 v = *(const float4*)(xbase + (long)(dc + d) * HW_SZ + i4);
                *(float4*)&As[d * NT + i4] = v;
            }
            // Stage B: 128 codes x 16 dims, transposed into [d][k]
#pragma unroll
            for (int l = 0; l < 2; ++l) {
                int t  = tid + l * 256;          // 0..511
                int k  = t >> 2;                 // 0..127
                int dq = (t & 3) * 4;            // 0,4,8,12
                float4 v = *(const float4*)(w + (long)(kc + k) * DDIM + dc + dq);
                Bs[(dq + 0) * KT + k] = v.x;
                Bs[(dq + 1) * KT + k] = v.y;
                Bs[(dq + 2) * KT + k] = v.z;
                Bs[(dq + 3) * KT + k] = v.w;
            }
            __syncthreads();
#pragma unroll
            for (int d = 0; d < DK; ++d) {
                float a[8], bb[8];
                *(float4*)&a[0]  = *(const float4*)&As[d * NT + ty * 8];
                *(float4*)&a[4]  = *(const float4*)&As[d * NT + ty * 8 + 4];
                *(float4*)&bb[0] = *(const float4*)&Bs[d * KT + tx * 8];
                *(float4*)&bb[4] = *(const float4*)&Bs[d * KT + tx * 8 + 4];
#pragma unroll
                for (int i = 0; i < 8; ++i)
#pragma unroll
                    for (int j = 0; j < 8; ++j) acc[i][j] += a[i] * bb[j];
            }
            __syncthreads();
        }

        // fold K-chunk into running best (ascending k => first-min tie-break)
#pragma unroll
        for (int j = 0; j < 8; ++j) {
            int   k  = kc + tx * 8 + j;
            float wn = wnorm[k];
#pragma unroll
            for (int i = 0; i < 8; ++i) {
                float dist = wn - 2.0f * acc[i][j];
                if (dist < best[i]) { best[i] = dist; bidx[i] = k; }
            }
        }
    }

    // cross-tx argmin reduction; overlay smem (padded stride NT+1: conflict-free)
    __syncthreads();
    float* rv = smem;                         // [16][NT+1]
    int*   ri = (int*)(smem + 16 * (NT + 1)); // [16][NT+1]
#pragma unroll
    for (int i = 0; i < 8; ++i) {
        rv[tx * (NT + 1) + ty * 8 + i] = best[i];
        ri[tx * (NT + 1) + ty * 8 + i] = bidx[i];
    }
    __syncthreads();
    if (tid < NT) {
        float bv = rv[tid];
        int   bi = ri[tid];
#pragma unroll
        for (int t = 1; t < 16; ++t) {
            float v  = rv[t * (NT + 1) + tid];
            int   ii = ri[t * (NT + 1) + tid];
            if (v < bv || (v == bv && ii < bi)) { bv = v; bi = ii; }
        }
        candv[ks * N_PTS + n0 + tid] = bv;
        candi[ks * N_PTS + n0 + tid] = bi;
    }
}

// ---------------------------------------------------------------------------
// merge: pick global argmin across the 4 K-split candidates (value, then index)
// ---------------------------------------------------------------------------
__global__ __launch_bounds__(256)
void merge_kernel(const float* __restrict__ candv, const int* __restrict__ candi,
                  int* __restrict__ idx, int* __restrict__ counts) {
    int n = blockIdx.x * 256 + threadIdx.x;      // < 32768
    float bv = candv[n];
    int   bi = candi[n];
#pragma unroll
    for (int s = 1; s < KSPLIT; ++s) {
        float v  = candv[s * N_PTS + n];
        int   ii = candi[s * N_PTS + n];
        if (v < bv || (v == bv && ii < bi)) { bv = v; bi = ii; }
    }
    idx[n] = bi;
    atomicAdd(&counts[bi], 1);
}

// ---------------------------------------------------------------------------
// gather: out[b][c][hw] = w[idx[n]][c] ; per-block partial loss (NO atomics)
// grid-stride: 1024 blocks x 256 threads, 8 float4 per thread
// ---------------------------------------------------------------------------
__global__ __launch_bounds__(256)
void gather_kernel(const float* __restrict__ x, const float* __restrict__ w,
                   const int* __restrict__ idx, float* __restrict__ out,
                   float* __restrict__ partial) {
    const int gid = blockIdx.x * 256 + threadIdx.x;
    float e = 0.f;
#pragma unroll
    for (int l = 0; l < 8; ++l) {
        int j4 = gid + l * GATHER_THREADS_TOT;   // float4 index, < 2097152
        int i  = j4 << 2;                        // flat BCHW element index
        int hw = i & 1023;
        int c  = (i >> 10) & 255;
        int b  = i >> 18;
        int n  = (b << 10) + hw;                 // 4 consecutive points
        float4 xv = *(const float4*)(x + i);
        float4 q;
        q.x = w[(long)idx[n + 0] * DDIM + c];
        q.y = w[(long)idx[n + 1] * DDIM + c];
        q.z = w[(long)idx[n + 2] * DDIM + c];
        q.w = w[(long)idx[n + 3] * DDIM + c];
        *(float4*)(out + i) = q;
        float dx = q.x - xv.x, dy = q.y - xv.y, dz = q.z - xv.z, dw = q.w - xv.w;
        e += dx * dx + dy * dy + dz * dz + dw * dw;
    }
    // wave64 reduce, then one LDS hop; single plain store per block
#pragma unroll
    for (int off = 32; off > 0; off >>= 1) e += __shfl_down(e, off, 64);
    __shared__ float wsum[4];
    int lane = threadIdx.x & 63, wid = threadIdx.x >> 6;
    if (lane == 0) wsum[wid] = e;
    __syncthreads();
    if (threadIdx.x == 0)
        partial[blockIdx.x] = wsum[0] + wsum[1] + wsum[2] + wsum[3];
}

// ---------------------------------------------------------------------------
// encodings: one-hot [N, K] float32 (enc base is 8B-aligned: ENC_OFF % 4 == 2)
// ---------------------------------------------------------------------------
__global__ __launch_bounds__(256)
void enc_kernel(const int* __restrict__ idx, float* __restrict__ enc) {
    const int t = blockIdx.x * 256 + threadIdx.x;    // < 8388608
    const int j = t * 4;
    const int n = j >> 10;
    const int k = j & 1023;
    const int id = idx[n];
    float2 v0, v1;
    v0.x = (k == id)     ? 1.f : 0.f;
    v0.y = (k + 1 == id) ? 1.f : 0.f;
    v1.x = (k + 2 == id) ? 1.f : 0.f;
    v1.y = (k + 3 == id) ? 1.f : 0.f;
    float2* p = (float2*)(enc + j);
    p[0] = v0;
    p[1] = v1;
}

// ---------------------------------------------------------------------------
// entropy + loss finalize: -sum p*log(p+1e-10) and COMMIT*mean(partials)
// ---------------------------------------------------------------------------
__global__ void entropy_kernel(const int* __restrict__ counts,
                               const float* __restrict__ partial,
                               float* __restrict__ out) {
    __shared__ float redE[256];
    __shared__ float redL[256];
    float se = 0.f, sl = 0.f;
#pragma unroll
    for (int l = 0; l < 4; ++l) {
        int k = threadIdx.x + l * 256;
        float p = (float)counts[k] * (1.0f / (float)N_PTS);
        se += p * logf(p + 1e-10f);
        sl += partial[k];
    }
    redE[threadIdx.x] = se;
    redL[threadIdx.x] = sl;
    __syncthreads();
    for (int off = 128; off > 0; off >>= 1) {
        if (threadIdx.x < off) {
            redE[threadIdx.x] += redE[threadIdx.x + off];
            redL[threadIdx.x] += redL[threadIdx.x + off];
        }
        __syncthreads();
    }
    if (threadIdx.x == 0) {
        out[ENT_OFF]  = -redE[0];
        out[LOSS_OFF] = redL[0] * (0.25f / (float)OUT_ELEMS);
    }
}

// ---------------------------------------------------------------------------
extern "C" void kernel_launch(void* const* d_in, const int* in_sizes, int n_in,
                              void* d_out, int out_size, void* d_ws, size_t ws_size,
                              hipStream_t stream) {
    const float* x = (const float*)d_in[0];   // [32,256,32,32] BCHW
    const float* w = (const float*)d_in[1];   // [1024,256]
    float* out = (float*)d_out;

    int*   idx     = (int*)d_ws;                    // [32768]
    int*   counts  = idx + N_PTS;                   // [1024]
    float* wnorm   = (float*)(counts + KCODES);     // [1024]
    float* partial = wnorm + KCODES;                // [1024]
    float* candv   = partial + GATHER_BLOCKS;       // [4][32768]
    int*   candi   = (int*)(candv + KSPLIT * N_PTS);// [4][32768]

    prep_kernel<<<4, 256, 0, stream>>>(w, wnorm, counts);
    argmin_kernel<<<dim3(N_PTS / NT, KSPLIT), 256, 0, stream>>>(x, w, wnorm, candv, candi);
    merge_kernel<<<N_PTS / 256, 256, 0, stream>>>(candv, candi, idx, counts);
    gather_kernel<<<GATHER_BLOCKS, 256, 0, stream>>>(x, w, idx, out, partial);
    enc_kernel<<<OUT_ELEMS / 256, 256, 0, stream>>>(idx, out + ENC_OFF);
    entropy_kernel<<<1, 256, 0, stream>>>(counts, partial, out);
}

// Round 3
// 380.201 us; speedup vs baseline: 2.3235x; 1.1894x over previous
//
#include <hip/hip_runtime.h>

// Problem constants
#define N_PTS   32768       // B*H*W
#define KCODES  1024
#define DDIM    256
#define OUT_ELEMS 8388608   // B*C*H*W
#define LOSS_OFF  8388608
#define ENT_OFF   8388609
#define ENC_OFF   8388610

typedef unsigned short ushort_t;
typedef unsigned short __attribute__((ext_vector_type(4))) us4;
typedef float  __attribute__((ext_vector_type(2))) f2v;
typedef float  __attribute__((ext_vector_type(4))) f4v;
typedef _Float16 __attribute__((ext_vector_type(8))) half8;

// ---- fp16 hi/lo split helpers (hi+lo carries 22 mantissa bits ~ fp32) ----
__device__ __forceinline__ ushort_t f2h_bits(float f) {
    union { _Float16 h; ushort_t u; } c; c.h = (_Float16)f; return c.u;
}
__device__ __forceinline__ float h2f(ushort_t u) {
    union { ushort_t u; _Float16 h; } c; c.u = u; return (float)c.h;
}

// async global->LDS, 16B per lane (dest = wave-uniform base + lane*16)
__device__ __forceinline__ void lds16(const void* g, void* l) {
    __builtin_amdgcn_global_load_lds((const __attribute__((address_space(1))) void*)g,
                                     (__attribute__((address_space(3))) void*)l,
                                     16, 0, 0);
}

// ---------------------------------------------------------------------------
// split_x: x BCHW fp32 -> Ah/Al [n][d] fp16 bits (transpose via LDS tile)
// ---------------------------------------------------------------------------
__global__ __launch_bounds__(256)
void split_x_kernel(const float* __restrict__ x, ushort_t* __restrict__ Ah,
                    ushort_t* __restrict__ Al) {
    __shared__ ushort_t hiT[64][65];
    __shared__ ushort_t loT[64][65];
    const int bb  = blockIdx.z;
    const int hw0 = blockIdx.x * 64;
    const int c0  = blockIdx.y * 64;
    const int t   = threadIdx.x;
    const int ci  = t >> 2;
    const int seg = t & 3;
    const float* xr = x + ((long)bb * 256 + c0 + ci) * 1024 + hw0;
#pragma unroll
    for (int it = 0; it < 4; ++it) {
        const int hwj = (seg + it * 4) * 4;
        f4v v = *(const f4v*)(xr + hwj);
#pragma unroll
        for (int e = 0; e < 4; ++e) {
            float fv = v[e];
            ushort_t h = f2h_bits(fv);
            hiT[hwj + e][ci] = h;
            loT[hwj + e][ci] = f2h_bits(fv - h2f(h));
        }
    }
    __syncthreads();
    const int hwj = t >> 2;
    const long n = (long)bb * 1024 + hw0 + hwj;
#pragma unroll
    for (int it = 0; it < 4; ++it) {
        const int cb = (seg + it * 4) * 4;
        us4 hv, lv;
#pragma unroll
        for (int e = 0; e < 4; ++e) { hv[e] = hiT[hwj][cb + e]; lv[e] = loT[hwj][cb + e]; }
        *(us4*)(Ah + n * 256 + c0 + cb) = hv;
        *(us4*)(Al + n * 256 + c0 + cb) = lv;
    }
}

// ---------------------------------------------------------------------------
// prep_w: Wh/Wl fp16 split (layout already [k][d]); wnorm fp32; zero counts
// ---------------------------------------------------------------------------
__global__ __launch_bounds__(256)
void prep_w_kernel(const float* __restrict__ w, ushort_t* __restrict__ Wh,
                   ushort_t* __restrict__ Wl, float* __restrict__ wnorm,
                   int* __restrict__ counts) {
    const int k = blockIdx.x * 256 + threadIdx.x;
    const float* wr = w + (long)k * DDIM;
    float s = 0.f;
    for (int d = 0; d < DDIM; d += 4) {
        f4v v = *(const f4v*)(wr + d);
        s += v[0]*v[0] + v[1]*v[1] + v[2]*v[2] + v[3]*v[3];
        us4 hv, lv;
#pragma unroll
        for (int e = 0; e < 4; ++e) {
            ushort_t h = f2h_bits(v[e]);
            hv[e] = h;
            lv[e] = f2h_bits(v[e] - h2f(h));
        }
        *(us4*)(Wh + (long)k * DDIM + d) = hv;
        *(us4*)(Wl + (long)k * DDIM + d) = lv;
    }
    wnorm[k] = s;
    counts[k] = 0;
}

// ---------------------------------------------------------------------------
// argmin via MFMA: S = Xh.WhT + Xh.WlT + Xl.WhT (K=768 fp16 GEMM, fp32 acc)
// dist = ||w||^2 - 2S (||x||^2 constant per point). Block: 128 pts x 128
// codes, 4 waves each 64x64 (4x4 tiles of 16x16x32). N-split 8 -> merge.
// ---------------------------------------------------------------------------
__global__ __launch_bounds__(256)
void argmin_mfma_kernel(const ushort_t* __restrict__ Ah, const ushort_t* __restrict__ Al,
                        const ushort_t* __restrict__ Wh, const ushort_t* __restrict__ Wl,
                        const float* __restrict__ wnorm,
                        float* __restrict__ candv, int* __restrict__ candi) {
    __shared__ ushort_t As[128 * 32];   // [m][k] rows of 32 halves (64B)
    __shared__ ushort_t Bs[128 * 32];   // [n][k]
    __shared__ float redv[2][128];
    __shared__ int   redi[2][128];

    const int tid  = threadIdx.x;
    const int lane = tid & 63;
    const int wv   = tid >> 6;
    const int wm   = (wv & 1) * 64;     // wave's point offset
    const int wn   = (wv >> 1) * 64;    // wave's code offset
    const int q    = lane >> 4;
    const int ln   = lane & 15;
    const int n0   = blockIdx.x * 128;  // point base
    const int kb   = blockIdx.y * 128;  // code base

    const int rowS = tid >> 2;          // staging: 4 lanes x 16B per 64B row
    const int segS = tid & 3;

    f4v acc[4][4];
    const f4v zero4 = {0.f, 0.f, 0.f, 0.f};
#pragma unroll
    for (int i = 0; i < 4; ++i)
#pragma unroll
        for (int j = 0; j < 4; ++j) acc[i][j] = zero4;

    const long aoff1 = ((long)(n0 + rowS) * DDIM + segS * 8) * 2;
    const long aoff2 = ((long)(n0 + 64 + rowS) * DDIM + segS * 8) * 2;
    const long boff1 = ((long)(kb + rowS) * DDIM + segS * 8) * 2;
    const long boff2 = ((long)(kb + 64 + rowS) * DDIM + segS * 8) * 2;
    char* lA1 = (char*)As + tid * 16;
    char* lA2 = (char*)As + (tid + 256) * 16;
    char* lB1 = (char*)Bs + tid * 16;
    char* lB2 = (char*)Bs + (tid + 256) * 16;

    const char* APh[3] = {(const char*)Ah, (const char*)Ah, (const char*)Al};
    const char* BPh[3] = {(const char*)Wh, (const char*)Wl, (const char*)Wh};

#pragma unroll 1
    for (int ph = 0; ph < 3; ++ph) {
        const char* Ag = APh[ph];
        const char* Bg = BPh[ph];
#pragma unroll 1
        for (int kk = 0; kk < 8; ++kk) {
            const long dby = (long)kk * 64;   // 32 halves per K-step
            __syncthreads();                  // prev reads done before overwrite
            lds16(Ag + aoff1 + dby, lA1);
            lds16(Ag + aoff2 + dby, lA2);
            lds16(Bg + boff1 + dby, lB1);
            lds16(Bg + boff2 + dby, lB2);
            __syncthreads();                  // staging drained (vmcnt before barrier)
            half8 a[4], b[4];
#pragma unroll
            for (int i = 0; i < 4; ++i)
                a[i] = *(const half8*)(As + (wm + i * 16 + ln) * 32 + q * 8);
#pragma unroll
            for (int j = 0; j < 4; ++j)
                b[j] = *(const half8*)(Bs + (wn + j * 16 + ln) * 32 + q * 8);
#pragma unroll
            for (int i = 0; i < 4; ++i)
#pragma unroll
                for (int j = 0; j < 4; ++j)
                    acc[i][j] = __builtin_amdgcn_mfma_f32_16x16x32_f16(a[i], b[j], acc[i][j], 0, 0, 0);
        }
    }

    // ---- argmin fold. C/D layout: col(n)=lane&15, row(m)=(lane>>4)*4+reg ----
    float bv[4][4]; int bi[4][4];
#pragma unroll
    for (int i = 0; i < 4; ++i)
#pragma unroll
        for (int r = 0; r < 4; ++r) { bv[i][r] = 3.402823466e38f; bi[i][r] = 0; }
#pragma unroll
    for (int j = 0; j < 4; ++j) {          // ascending code idx => first-min tiebreak
        const int n_g = kb + wn + j * 16 + ln;
        const float wnv = wnorm[n_g];
#pragma unroll
        for (int i = 0; i < 4; ++i)
#pragma unroll
            for (int r = 0; r < 4; ++r) {
                float dist = wnv - 2.0f * acc[i][j][r];
                if (dist < bv[i][r]) { bv[i][r] = dist; bi[i][r] = n_g; }
            }
    }
    // cross-lane (16 lanes of same q hold same point, different codes)
#pragma unroll
    for (int m = 1; m < 16; m <<= 1) {
#pragma unroll
        for (int i = 0; i < 4; ++i)
#pragma unroll
            for (int r = 0; r < 4; ++r) {
                float ov = __shfl_xor(bv[i][r], m, 64);
                int   oi = __shfl_xor(bi[i][r], m, 64);
                if (ov < bv[i][r] || (ov == bv[i][r] && oi < bi[i][r])) {
                    bv[i][r] = ov; bi[i][r] = oi;
                }
            }
    }
    const int wg = wv >> 1;
    if (ln == 0) {
#pragma unroll
        for (int i = 0; i < 4; ++i)
#pragma unroll
            for (int r = 0; r < 4; ++r) {
                const int p = wm + i * 16 + q * 4 + r;
                redv[wg][p] = bv[i][r];
                redi[wg][p] = bi[i][r];
            }
    }
    __syncthreads();
    if (tid < 128) {
        float v0 = redv[0][tid]; int i0 = redi[0][tid];
        float v1 = redv[1][tid]; int i1 = redi[1][tid];
        if (v1 < v0) { v0 = v1; i0 = i1; }   // wg1 codes always higher idx
        candv[blockIdx.y * N_PTS + n0 + tid] = v0;
        candi[blockIdx.y * N_PTS + n0 + tid] = i0;
    }
}

// ---------------------------------------------------------------------------
// merge: argmin across S split candidates (value, then lowest index)
// ---------------------------------------------------------------------------
__global__ __launch_bounds__(256)
void merge_kernel(const float* __restrict__ candv, const int* __restrict__ candi,
                  int* __restrict__ idx, int* __restrict__ counts, int S) {
    int n = blockIdx.x * 256 + threadIdx.x;
    float bv = candv[n];
    int   bi = candi[n];
    for (int s = 1; s < S; ++s) {
        float v  = candv[s * N_PTS + n];
        int   ii = candi[s * N_PTS + n];
        if (v < bv || (v == bv && ii < bi)) { bv = v; bi = ii; }
    }
    idx[n] = bi;
    atomicAdd(&counts[bi], 1);
}

// ---------------------------------------------------------------------------
// gather: out = w[idx] in BCHW; per-block partial commitment loss (no atomics)
// ---------------------------------------------------------------------------
#define GATHER_BLOCKS 1024
#define GATHER_THREADS_TOT (GATHER_BLOCKS * 256)

__global__ __launch_bounds__(256)
void gather_kernel(const float* __restrict__ x, const float* __restrict__ w,
                   const int* __restrict__ idx, float* __restrict__ out,
                   float* __restrict__ partial) {
    const int gid = blockIdx.x * 256 + threadIdx.x;
    float e = 0.f;
#pragma unroll
    for (int l = 0; l < 8; ++l) {
        int j4 = gid + l * GATHER_THREADS_TOT;
        int i  = j4 << 2;
        int hw = i & 1023;
        int c  = (i >> 10) & 255;
        int b  = i >> 18;
        int n  = (b << 10) + hw;
        f4v xv = *(const f4v*)(x + i);
        f4v q;
        q[0] = w[(long)idx[n + 0] * DDIM + c];
        q[1] = w[(long)idx[n + 1] * DDIM + c];
        q[2] = w[(long)idx[n + 2] * DDIM + c];
        q[3] = w[(long)idx[n + 3] * DDIM + c];
        __builtin_nontemporal_store(q, (f4v*)(out + i));
        f4v d = q - xv;
        e += d[0]*d[0] + d[1]*d[1] + d[2]*d[2] + d[3]*d[3];
    }
#pragma unroll
    for (int off = 32; off > 0; off >>= 1) e += __shfl_down(e, off, 64);
    __shared__ float wsum[4];
    int lane = threadIdx.x & 63, wid = threadIdx.x >> 6;
    if (lane == 0) wsum[wid] = e;
    __syncthreads();
    if (threadIdx.x == 0)
        partial[blockIdx.x] = wsum[0] + wsum[1] + wsum[2] + wsum[3];
}

// ---------------------------------------------------------------------------
// encodings: zero-fill (nontemporal) + scatter of ones
// (enc base is 8B-aligned: ENC_OFF % 4 == 2 -> float2 stores)
// ---------------------------------------------------------------------------
__global__ __launch_bounds__(256)
void enc_zero_kernel(float* __restrict__ enc) {
    const int gid = blockIdx.x * 256 + threadIdx.x;    // < 524288
    f2v z = {0.f, 0.f};
    f2v* p = (f2v*)enc;
#pragma unroll
    for (int it = 0; it < 32; ++it)
        __builtin_nontemporal_store(z, p + gid + it * 524288);
}

__global__ __launch_bounds__(256)
void enc_scatter_kernel(const int* __restrict__ idx, float* __restrict__ enc) {
    const int n = blockIdx.x * 256 + threadIdx.x;      // < 32768
    enc[(long)n * KCODES + idx[n]] = 1.0f;
}

// ---------------------------------------------------------------------------
// entropy + loss finalize
// ---------------------------------------------------------------------------
__global__ void entropy_kernel(const int* __restrict__ counts,
                               const float* __restrict__ partial,
                               float* __restrict__ out) {
    __shared__ float redE[256];
    __shared__ float redL[256];
    float se = 0.f, sl = 0.f;
#pragma unroll
    for (int l = 0; l < 4; ++l) {
        int k = threadIdx.x + l * 256;
        float p = (float)counts[k] * (1.0f / (float)N_PTS);
        se += p * logf(p + 1e-10f);
        sl += partial[k];
    }
    redE[threadIdx.x] = se;
    redL[threadIdx.x] = sl;
    __syncthreads();
    for (int off = 128; off > 0; off >>= 1) {
        if (threadIdx.x < off) {
            redE[threadIdx.x] += redE[threadIdx.x + off];
            redL[threadIdx.x] += redL[threadIdx.x + off];
        }
        __syncthreads();
    }
    if (threadIdx.x == 0) {
        out[ENT_OFF]  = -redE[0];
        out[LOSS_OFF] = redL[0] * (0.25f / (float)OUT_ELEMS);
    }
}

// ===========================================================================
// Fallback fp32 path (R2's proven kernels) — used only if ws_size too small
// ===========================================================================
#define FNT 128
#define FKT 128
#define FDK 16

__global__ void prep_fp32_kernel(const float* __restrict__ w, float* __restrict__ wnorm,
                                 int* __restrict__ counts) {
    int k = blockIdx.x * 256 + threadIdx.x;
    if (k < KCODES) {
        const float4* wr = (const float4*)(w + (long)k * DDIM);
        float s = 0.f;
#pragma unroll 8
        for (int i = 0; i < DDIM / 4; ++i) {
            float4 v = wr[i];
            s += v.x * v.x + v.y * v.y + v.z * v.z + v.w * v.w;
        }
        wnorm[k]  = s;
        counts[k] = 0;
    }
}

__global__ __launch_bounds__(256)
void argmin_fp32_kernel(const float* __restrict__ x, const float* __restrict__ w,
                        const float* __restrict__ wnorm,
                        float* __restrict__ candv, int* __restrict__ candi) {
    __shared__ float smem[4160];
    float* As = smem;
    float* Bs = smem + FDK * FNT;

    const int tid = threadIdx.x;
    const int tx  = tid & 15;
    const int ty  = tid >> 4;
    const int n0  = blockIdx.x * FNT;
    const int ks  = blockIdx.y;
    const int b   = n0 >> 10;
    const int hw0 = n0 & 1023;
    const float* xbase = x + (long)b * (256 * 1024) + hw0;

    float best[8];
    int   bidx[8];
#pragma unroll
    for (int i = 0; i < 8; ++i) { best[i] = 3.402823466e38f; bidx[i] = 0; }

    for (int kc = ks * 256; kc < ks * 256 + 256; kc += FKT) {
        float accf[8][8];
#pragma unroll
        for (int i = 0; i < 8; ++i)
#pragma unroll
            for (int j = 0; j < 8; ++j) accf[i][j] = 0.f;

        for (int dc = 0; dc < DDIM; dc += FDK) {
#pragma unroll
            for (int l = 0; l < 2; ++l) {
                int t  = tid + l * 256;
                int d  = t >> 5;
                int i4 = (t & 31) * 4;
                float4 v = *(const float4*)(xbase + (long)(dc + d) * 1024 + i4);
                *(float4*)&As[d * FNT + i4] = v;
            }
#pragma unroll
            for (int l = 0; l < 2; ++l) {
                int t  = tid + l * 256;
                int k  = t >> 2;
                int dq = (t & 3) * 4;
                float4 v = *(const float4*)(w + (long)(kc + k) * DDIM + dc + dq);
                Bs[(dq + 0) * FKT + k] = v.x;
                Bs[(dq + 1) * FKT + k] = v.y;
                Bs[(dq + 2) * FKT + k] = v.z;
                Bs[(dq + 3) * FKT + k] = v.w;
            }
            __syncthreads();
#pragma unroll
            for (int d = 0; d < FDK; ++d) {
                float a[8], bb[8];
                *(float4*)&a[0]  = *(const float4*)&As[d * FNT + ty * 8];
                *(float4*)&a[4]  = *(const float4*)&As[d * FNT + ty * 8 + 4];
                *(float4*)&bb[0] = *(const float4*)&Bs[d * FKT + tx * 8];
                *(float4*)&bb[4] = *(const float4*)&Bs[d * FKT + tx * 8 + 4];
#pragma unroll
                for (int i = 0; i < 8; ++i)
#pragma unroll
                    for (int j = 0; j < 8; ++j) accf[i][j] += a[i] * bb[j];
            }
            __syncthreads();
        }
#pragma unroll
        for (int j = 0; j < 8; ++j) {
            int   k  = kc + tx * 8 + j;
            float wn = wnorm[k];
#pragma unroll
            for (int i = 0; i < 8; ++i) {
                float dist = wn - 2.0f * accf[i][j];
                if (dist < best[i]) { best[i] = dist; bidx[i] = k; }
            }
        }
    }
    __syncthreads();
    float* rv = smem;
    int*   ri = (int*)(smem + 16 * (FNT + 1));
#pragma unroll
    for (int i = 0; i < 8; ++i) {
        rv[tx * (FNT + 1) + ty * 8 + i] = best[i];
        ri[tx * (FNT + 1) + ty * 8 + i] = bidx[i];
    }
    __syncthreads();
    if (tid < FNT) {
        float bvv = rv[tid];
        int   bii = ri[tid];
#pragma unroll
        for (int t = 1; t < 16; ++t) {
            float v  = rv[t * (FNT + 1) + tid];
            int   ii = ri[t * (FNT + 1) + tid];
            if (v < bvv || (v == bvv && ii < bii)) { bvv = v; bii = ii; }
        }
        candv[ks * N_PTS + n0 + tid] = bvv;
        candi[ks * N_PTS + n0 + tid] = bii;
    }
}

// ---------------------------------------------------------------------------
extern "C" void kernel_launch(void* const* d_in, const int* in_sizes, int n_in,
                              void* d_out, int out_size, void* d_ws, size_t ws_size,
                              hipStream_t stream) {
    const float* x = (const float*)d_in[0];   // [32,256,32,32] BCHW
    const float* w = (const float*)d_in[1];   // [1024,256]
    float* out = (float*)d_out;
    char*  ws  = (char*)d_ws;

    // mfma-path workspace layout (bytes)
    const size_t AH_OFF  = 0;                        // 32768*256*2 = 16 MB
    const size_t AL_OFF  = AH_OFF + 16777216;
    const size_t WH_OFF  = AL_OFF + 16777216;        // 1024*256*2 = 512 KB
    const size_t WL_OFF  = WH_OFF + 524288;
    const size_t WN_OFF  = WL_OFF + 524288;          // wnorm 4 KB
    const size_t IDX_OFF = WN_OFF + 4096;            // idx 128 KB
    const size_t CNT_OFF = IDX_OFF + 131072;         // counts 4 KB
    const size_t PAR_OFF = CNT_OFF + 4096;           // partial 4 KB
    const size_t CV_OFF  = PAR_OFF + 4096;           // candv 8 splits
    const size_t CI_OFF  = CV_OFF + 8 * (size_t)N_PTS * 4;
    const size_t NEED    = CI_OFF + 8 * (size_t)N_PTS * 4;

    int*   idx;
    int*   counts;
    float* partial;

    if (ws_size >= NEED) {
        ushort_t* Ah    = (ushort_t*)(ws + AH_OFF);
        ushort_t* Al    = (ushort_t*)(ws + AL_OFF);
        ushort_t* Wh    = (ushort_t*)(ws + WH_OFF);
        ushort_t* Wl    = (ushort_t*)(ws + WL_OFF);
        float*    wnorm = (float*)(ws + WN_OFF);
        float*    candv = (float*)(ws + CV_OFF);
        int*      candi = (int*)(ws + CI_OFF);
        idx     = (int*)(ws + IDX_OFF);
        counts  = (int*)(ws + CNT_OFF);
        partial = (float*)(ws + PAR_OFF);

        split_x_kernel<<<dim3(16, 4, 32), 256, 0, stream>>>(x, Ah, Al);
        prep_w_kernel<<<4, 256, 0, stream>>>(w, Wh, Wl, wnorm, counts);
        argmin_mfma_kernel<<<dim3(256, 8), 256, 0, stream>>>(Ah, Al, Wh, Wl, wnorm,
                                                             candv, candi);
        merge_kernel<<<N_PTS / 256, 256, 0, stream>>>(candv, candi, idx, counts, 8);
    } else {
        // compact fallback layout (R2's fp32 path)
        idx             = (int*)ws;
        counts          = idx + N_PTS;
        float* wnorm    = (float*)(counts + KCODES);
        partial         = wnorm + KCODES;
        float* candv    = partial + GATHER_BLOCKS;
        int*   candi    = (int*)(candv + 4 * N_PTS);

        prep_fp32_kernel<<<4, 256, 0, stream>>>(w, wnorm, counts);
        argmin_fp32_kernel<<<dim3(N_PTS / FNT, 4), 256, 0, stream>>>(x, w, wnorm,
                                                                     candv, candi);
        merge_kernel<<<N_PTS / 256, 256, 0, stream>>>(candv, candi, idx, counts, 4);
    }

    gather_kernel<<<GATHER_BLOCKS, 256, 0, stream>>>(x, w, idx, out, partial);
    enc_zero_kernel<<<2048, 256, 0, stream>>>(out + ENC_OFF);
    enc_scatter_kernel<<<N_PTS / 256, 256, 0, stream>>>(idx, out + ENC_OFF);
    entropy_kernel<<<1, 256, 0, stream>>>(counts, partial, out);
}